// Round 6
// baseline (145.751 us; speedup 1.0000x reference)
//
#include <hip/hip_runtime.h>
#include <hip/hip_fp16.h>
#include <math.h>

#define N_VAR 8192
#define N_CHK 4096
#define DC 6
#define N_EDGE 24576          // N_VAR*3 == N_CHK*6
#define BATCH 512
#define N_ITER 5
#define CLIP_F 0.99999988f    // float32(1 - 1e-7), matches jnp/np clip in fp32
#define NTHREADS 1024
#define VPT (N_VAR / NTHREADS)   // 8 vars per thread
#define CPT (N_CHK / NTHREADS)   // 4 checks per thread

// fp16 sqrt-domain clamp: keep s in fp16 normal range
#define S_MIN 6.2e-5f
#define S_MAX 6.0e4f

// ---- workspace layout: [0, N_CHK) int counters | [N_CHK, N_CHK + N_CHK*DC) chk LDS-indices ----

__global__ void k_zero(int* __restrict__ cnt) {
    int i = blockIdx.x * blockDim.x + threadIdx.x;
    if (i < N_CHK) cnt[i] = 0;
}

__global__ void k_build(const int* __restrict__ chk_index,
                        int* __restrict__ cnt,
                        int* __restrict__ chk_edges) {
    int e = blockIdx.x * blockDim.x + threadIdx.x;
    if (e < N_EDGE) {
        int c = chk_index[e];
        int p = atomicAdd(&cnt[c], 1);
        // slot order within a check is irrelevant (LOO product is symmetric).
        // Store the LDS halfword index: SoA planes m[j*N_VAR + v], e -> (v=e/3, j=e%3).
        int v = e / 3, j = e - 3 * v;
        chk_edges[c * DC + p] = j * N_VAR + v;
    }
}

// fp16 sqrt-domain SPA: LDS m[] (48 KB -> 2 blocks/CU, 32 waves/CU) alternates
//   s = sqrt(E) = sqrt(exp(msg))  (var phase out)
//   s = sqrt(q) = sqrt(exp(ext))  (check phase out)
// sqrt halves the log-domain range (fits fp16 normals) and halves the stored
// relative error (rho_E ~ 1e-3 after squaring). Var phase is mul-only:
// sqrt(E0) = sqrt(el)*s1*s2; out = 2*log(sel*s0*s1*s2). Check phase:
// t=(E-1)/(E+1), LOO prefix/suffix, q=(1+lo)/(1-lo), store sqrt(q).
// No zero-sign special case: a t rounded to exactly 0 gives the other edges
// q=1 (ext=0) vs true |ext|<=2|t|~1e-3 — bounded; fp32-reference t==0 is
// measure-zero. Deep saturation (|msg|>~17): both ref and ours round t to +-1
// and land on the same CLIP_F constant.
__launch_bounds__(1024, 8)   // 8 waves/EU => 2 blocks/CU; VGPR capped at 64
__global__ void k_spa(const float* __restrict__ llr,
                      const int* __restrict__ chk_edges,
                      float* __restrict__ out) {
    __shared__ __half m[N_EDGE];   // 48 KB
    const int b = blockIdx.x;
    const int tid = threadIdx.x;
    const float* __restrict__ lrow = llr + (size_t)b * N_VAR;
    float* __restrict__ orow = out + (size_t)b * N_VAR;

    // only persistent per-thread state: sel = sqrt(exp(llr)) = exp(llr/2)
    float sel[VPT];
    #pragma unroll
    for (int k = 0; k < VPT; ++k)
        sel[k] = __expf(0.5f * lrow[tid + k * NTHREADS]);

    // ---- iter-0 var phase: ext=0 -> E=exp(llr) -> s=sel on all 3 planes ----
    #pragma unroll
    for (int k = 0; k < VPT; ++k) {
        int v = tid + k * NTHREADS;
        __half h = __float2half(sel[k]);   // sel in [5.5e-3, 181]: no clamp needed
        m[v] = h; m[N_VAR + v] = h; m[2 * N_VAR + v] = h;
    }
    __syncthreads();

    #pragma unroll 1
    for (int iter = 0; iter < N_ITER; ++iter) {
        // ---- check phase: gather 6 s, t=(s^2-1)/(s^2+1), LOO, scatter 6 sqrt(q) ----
        #pragma unroll 1
        for (int k = 0; k < CPT; ++k) {
            int c = tid + k * NTHREADS;
            const int* __restrict__ ep = chk_edges + c * DC;
            int   idx[DC];
            float t[DC];
            #pragma unroll
            for (int j = 0; j < DC; ++j) idx[j] = ep[j];
            #pragma unroll
            for (int j = 0; j < DC; ++j) {
                float s = __half2float(m[idx[j]]);
                float E = s * s;
                t[j] = (E - 1.0f) * __builtin_amdgcn_rcpf(E + 1.0f);
            }
            float pre[DC + 1], suf[DC + 1];
            pre[0] = 1.0f; suf[DC] = 1.0f;
            #pragma unroll
            for (int j = 0; j < DC; ++j)      pre[j + 1] = pre[j] * t[j];
            #pragma unroll
            for (int j = DC - 1; j >= 0; --j) suf[j] = suf[j + 1] * t[j];
            #pragma unroll
            for (int j = 0; j < DC; ++j) {
                float lo = pre[j] * suf[j + 1];
                lo = fminf(fmaxf(lo, -CLIP_F), CLIP_F);
                float q = (1.0f + lo) * __builtin_amdgcn_rcpf(1.0f - lo);
                m[idx[j]] = __float2half(__builtin_amdgcn_sqrtf(q));  // sqrt(q) in [2.4e-4, 4084]
            }
        }
        __syncthreads();

        // ---- var phase: contiguous plane reads, mul-only except the output log ----
        const bool last = (iter == N_ITER - 1);
        #pragma unroll 1
        for (int k = 0; k < VPT; ++k) {
            int v = tid + k * NTHREADS;
            float s0 = __half2float(m[v]);
            float s1 = __half2float(m[N_VAR + v]);
            float s2 = __half2float(m[2 * N_VAR + v]);
            float s01 = s0 * s1, s12 = s1 * s2, s02 = s0 * s2;
            // marginal: llr + sum(ext) = log(el*q0q1q2) = 2*log(sel*s0*s1*s2)
            orow[(size_t)iter * (BATCH * N_VAR) + v] = 2.0f * __logf(sel[k] * s01 * s2);
            if (!last) {
                float e0 = sel[k] * s12, e1 = sel[k] * s02, e2 = sel[k] * s01;
                m[v]             = __float2half(fminf(fmaxf(e0, S_MIN), S_MAX));
                m[N_VAR + v]     = __float2half(fminf(fmaxf(e1, S_MIN), S_MAX));
                m[2 * N_VAR + v] = __float2half(fminf(fmaxf(e2, S_MIN), S_MAX));
            }
        }
        if (!last) __syncthreads();
    }
}

extern "C" void kernel_launch(void* const* d_in, const int* in_sizes, int n_in,
                              void* d_out, int out_size, void* d_ws, size_t ws_size,
                              hipStream_t stream) {
    const float* llr       = (const float*)d_in[0];
    // d_in[1] = var_index: deterministic repeat(arange(N_VAR),3) — structure used directly
    const int*   chk_index = (const int*)d_in[2];
    float*       out       = (float*)d_out;

    int* cnt       = (int*)d_ws;
    int* chk_edges = cnt + N_CHK;

    k_zero <<<(N_CHK  + 255) / 256, 256, 0, stream>>>(cnt);
    k_build<<<(N_EDGE + 255) / 256, 256, 0, stream>>>(chk_index, cnt, chk_edges);
    k_spa  <<<BATCH, 1024, 0, stream>>>(llr, chk_edges, out);
}